// Round 7
// baseline (1001.018 us; speedup 1.0000x reference)
//
#include <hip/hip_runtime.h>
#include <hip/hip_cooperative_groups.h>

namespace cg = cooperative_groups;

#define NODES 50000
#define EDGES 800000
#define HID   128
#define HEADS 4
// DK = 32, scale = 1/sqrt(32)
#define SCORE_SCALE 0.17677669529663687f

#define NBUCK ((NODES + 255) >> 8)   // 196 buckets of 256 src nodes
#define CHUNK 4096

#define COOP_BLOCKS 1024
#define NPW 13                        // nodes per wave: 1024*4*13 = 53248 >= N

typedef unsigned int       u32;
typedef unsigned short     u16;
typedef unsigned long long u64;

typedef __attribute__((ext_vector_type(8))) short bf16x8;
typedef __attribute__((ext_vector_type(4))) float f32x4;

// round-to-nearest-even f32 -> bf16
__device__ __forceinline__ u16 f2bf(float f) {
    u32 u = __builtin_bit_cast(u32, f);
    return (u16)((u + 0x7FFFu + ((u >> 16) & 1u)) >> 16);
}
__device__ __forceinline__ float bflo(u32 u) { return __builtin_bit_cast(float, u << 16); }
__device__ __forceinline__ float bfhi(u32 u) { return __builtin_bit_cast(float, u & 0xFFFF0000u); }
__device__ __forceinline__ float bdot2(u32 a, u32 b) {
    return bflo(a) * bflo(b) + bfhi(a) * bfhi(b);
}

// ---------------------------------------------------------------------------
// W prep: Wt[n][k] = bf16(W[k][n]), both 128x128. 2 matrices.
// ---------------------------------------------------------------------------
__global__ __launch_bounds__(256) void wprep(
    const float* __restrict__ Wq, const float* __restrict__ Wk,
    u16* __restrict__ Wqt, u16* __restrict__ Wkt)
{
    int e   = blockIdx.x * 256 + threadIdx.x;
    int mat = e >> 14;
    int idx = e & 16383;
    int k  = idx >> 7;
    int nn = idx & 127;
    const float* W = mat ? Wk : Wq;
    u16*        Wt = mat ? Wkt : Wqt;
    Wt[nn * 128 + k] = f2bf(W[idx]);
}

// ---------------------------------------------------------------------------
// MFMA Q/K projection. Wave = one 16-row tile, both matrices.
// Also emits row-major bf16 copy of x.
// ---------------------------------------------------------------------------
__global__ __launch_bounds__(256) void gemm_qk_mfma(
    const float* __restrict__ x,
    const u16* __restrict__ Wqt, const float* __restrict__ bq,
    const u16* __restrict__ Wkt, const float* __restrict__ bk,
    u16* __restrict__ qb, u16* __restrict__ kb, u16* __restrict__ xb, int n)
{
    const int l  = threadIdx.x & 63;
    const int w  = threadIdx.x >> 6;
    const int lr = l & 15;
    const int kg = l >> 4;

    const int arow   = blockIdx.x * 64 + w * 16 + lr;
    const bool av    = (arow < n);
    const int  arowc = av ? arow : (n - 1);

    bf16x8 afrag[4];
    #pragma unroll
    for (int ks = 0; ks < 4; ++ks) {
        const float* px = x + (size_t)arowc * HID + ks * 32 + kg * 8;
        float4 p0 = *(const float4*)px;
        float4 p1 = *(const float4*)(px + 4);
        uint4 pk;
        pk.x = (u32)f2bf(p0.x) | ((u32)f2bf(p0.y) << 16);
        pk.y = (u32)f2bf(p0.z) | ((u32)f2bf(p0.w) << 16);
        pk.z = (u32)f2bf(p1.x) | ((u32)f2bf(p1.y) << 16);
        pk.w = (u32)f2bf(p1.z) | ((u32)f2bf(p1.w) << 16);
        afrag[ks] = __builtin_bit_cast(bf16x8, pk);
        if (av) *(uint4*)(xb + (size_t)arow * HID + ks * 32 + kg * 8) = pk;
    }

    #pragma unroll
    for (int mat = 0; mat < 2; ++mat) {
        const u16*   Wt   = mat ? Wkt : Wqt;
        const float* bias = mat ? bk : bq;
        u16*         outp = mat ? kb : qb;

        #pragma unroll
        for (int cb = 0; cb < 8; ++cb) {
            float bc = bias[cb * 16 + lr];
            f32x4 acc = {bc, bc, bc, bc};
            #pragma unroll
            for (int ks = 0; ks < 4; ++ks) {
                bf16x8 bfrag = __builtin_bit_cast(bf16x8,
                    *(const uint4*)(Wt + (size_t)(cb * 16 + lr) * 128 + ks * 32 + kg * 8));
                acc = __builtin_amdgcn_mfma_f32_16x16x32_bf16(afrag[ks], bfrag, acc, 0, 0, 0);
            }
            #pragma unroll
            for (int reg = 0; reg < 4; ++reg) {
                int gr = blockIdx.x * 64 + w * 16 + kg * 4 + reg;
                if (gr < n) outp[(size_t)gr * HID + cb * 16 + lr] = f2bf(acc[reg]);
            }
        }
    }
}

// ---------------------------------------------------------------------------
// out-degree histogram over src
// ---------------------------------------------------------------------------
__global__ __launch_bounds__(256) void hist_kernel(
    const int* __restrict__ ei, int* __restrict__ deg)
{
    int i = blockIdx.x * 256 + threadIdx.x;
    if (i < EDGES) atomicAdd(&deg[ei[i]], 1);
}

// ---------------------------------------------------------------------------
// two-level exclusive scan of deg -> off; also emits bucket cursors
// ---------------------------------------------------------------------------
__global__ __launch_bounds__(1024) void scan1(
    const int* __restrict__ deg, int* __restrict__ off,
    int* __restrict__ part, int n)
{
    __shared__ int sd[1024];
    int t = threadIdx.x, i = blockIdx.x * 1024 + t;
    int v = (i < n) ? deg[i] : 0;
    sd[t] = v;
    __syncthreads();
    #pragma unroll
    for (int o = 1; o < 1024; o <<= 1) {
        int a = (t >= o) ? sd[t - o] : 0;
        __syncthreads();
        sd[t] += a;
        __syncthreads();
    }
    if (i < n) off[i] = sd[t] - v;
    if (t == 1023) part[blockIdx.x] = sd[1023];
}

__global__ __launch_bounds__(64) void scan2(int* __restrict__ part,
                                            int* __restrict__ off_n, int nb)
{
    int t = threadIdx.x;
    int v = (t < nb) ? part[t] : 0;
    int orig = v;
    #pragma unroll
    for (int o = 1; o < 64; o <<= 1) {
        int a = __shfl_up(v, o);
        if (t >= o) v += a;
    }
    if (t < nb) part[t] = v - orig;
    if (t == 63) *off_n = v;
}

__global__ __launch_bounds__(1024) void scan3(
    int* __restrict__ off, int* __restrict__ bcur,
    const int* __restrict__ part, int n)
{
    int i = blockIdx.x * 1024 + threadIdx.x;
    if (i < n) {
        int o = off[i] + part[blockIdx.x];
        off[i] = o;
        if ((i & 255) == 0) bcur[i >> 8] = o;   // bucket base cursor
    }
}

// ---------------------------------------------------------------------------
// Phase 1: bin edges by bucket (src>>8) into tmp, bucket-contiguous.
// ---------------------------------------------------------------------------
__global__ __launch_bounds__(256) void bin_edges(
    const int* __restrict__ ei, int* __restrict__ bcur, u32* __restrict__ tmp)
{
    __shared__ u32 buf[CHUNK];
    __shared__ int hist[NBUCK];
    __shared__ int lcur[NBUCK];

    const int t  = threadIdx.x;
    const int e0 = blockIdx.x * CHUNK;
    const int e1 = (e0 + CHUNK < EDGES) ? e0 + CHUNK : EDGES;
    const int cnt = e1 - e0;

    for (int b = t; b < NBUCK; b += 256) hist[b] = 0;
    __syncthreads();

    for (int i = t; i < cnt; i += 256) {
        int src = ei[e0 + i];
        int dst = ei[EDGES + e0 + i];
        buf[i] = (u32)dst | ((u32)(src & 255) << 16) | ((u32)(src >> 8) << 24);
        atomicAdd(&hist[src >> 8], 1);
    }
    __syncthreads();

    for (int b = t; b < NBUCK; b += 256) {
        int h = hist[b];
        lcur[b] = h ? atomicAdd(&bcur[b], h) : 0;
    }
    __syncthreads();

    for (int i = t; i < cnt; i += 256) {
        u32 pk  = buf[i];
        int b   = pk >> 24;
        int pos = atomicAdd(&lcur[b], 1);
        tmp[pos] = pk & 0x00FFFFFFu;          // srcLocal<<16 | dst
    }
}

// ---------------------------------------------------------------------------
// Phase 2: exact CSR placement within each bucket (LDS cursors, local window)
// ---------------------------------------------------------------------------
__global__ __launch_bounds__(256) void place_edges(
    const u32* __restrict__ tmp, const int* __restrict__ off,
    u32* __restrict__ epack, int n)
{
    __shared__ int lcur[256];
    const int t     = threadIdx.x;
    const int nbase = blockIdx.x << 8;
    const int nend  = (nbase + 256 < n) ? nbase + 256 : n;

    if (nbase + t < nend) lcur[t] = off[nbase + t];
    __syncthreads();

    const int s0 = off[nbase];
    const int s1 = off[nend];
    for (int i = s0 + t; i < s1; i += 256) {
        u32 pk    = tmp[i];
        int local = pk >> 16;
        int pos   = atomicAdd(&lcur[local], 1);
        epack[pos] = pk & 0xFFFFu;            // dst only (att packed later)
    }
}

// ---------------------------------------------------------------------------
// CSR-ordered scores: wave per src node. q[src] loaded ONCE (sequential),
// only k[dst] gathered randomly.
// ---------------------------------------------------------------------------
__global__ __launch_bounds__(256) void score_csr(
    const u16* __restrict__ qb, const u16* __restrict__ kb,
    const int* __restrict__ off, const u32* __restrict__ ccol,
    float* __restrict__ evals, float* __restrict__ nsum, int n)
{
    const int wv   = (blockIdx.x * 256 + threadIdx.x) >> 6;   // src node
    const int lane = threadIdx.x & 63;
    const int l16  = lane & 15;
    const int grp  = lane >> 4;
    if (wv >= n) return;

    const int beg = off[wv];
    const int end = off[wv + 1];

    uint4 qv = *(const uint4*)(qb + (size_t)wv * HID + l16 * 8);

    #pragma unroll 2
    for (int j = beg; j < end; j += 4) {
        int e = j + grp;
        if (e < end) {
            u32 dst = ccol[e];
            uint4 kv = *(const uint4*)(kb + (size_t)dst * HID + l16 * 8);
            float p = bdot2(qv.x, kv.x) + bdot2(qv.y, kv.y) +
                      bdot2(qv.z, kv.z) + bdot2(qv.w, kv.w);
            p += __shfl_xor(p, 1);
            p += __shfl_xor(p, 2);
            if ((l16 & 3) == 0) {
                int head = l16 >> 2;
                float ev = __expf(p * SCORE_SCALE);
                evals[(size_t)e * HEADS + head] = ev;
                atomicAdd(&nsum[(size_t)dst * HEADS + head], ev);
            }
        }
    }
}

// ---------------------------------------------------------------------------
// head-mean attention; packs epack[pos] = dst | bf16(att)<<16 IN PLACE.
// ---------------------------------------------------------------------------
__global__ __launch_bounds__(256) void finalize_kernel(
    const float* __restrict__ evals, const float* __restrict__ nsum,
    u32* __restrict__ epack)
{
    int pos = blockIdx.x * 256 + threadIdx.x;
    if (pos >= EDGES) return;
    u32 dst = epack[pos];
    float4 ev = *(const float4*)(evals + (size_t)pos * HEADS);
    float4 sv = *(const float4*)(nsum  + (size_t)dst * HEADS);
    float am = 0.25f * (ev.x / (sv.x + 1e-16f) + ev.y / (sv.y + 1e-16f) +
                        ev.z / (sv.z + 1e-16f) + ev.w / (sv.w + 1e-16f));
    epack[pos] = dst | ((u32)f2bf(am) << 16);
}

// ---------------------------------------------------------------------------
// One Euler step for a wave's NPW nodes; fp32 state lives in LDS (zsh).
// outb != nullptr: intermediate step (update LDS + emit bf16 copy).
// outb == nullptr: final step (write fp32 out only).
// ---------------------------------------------------------------------------
__device__ __forceinline__ void euler_step(
    int lane, int base, int n,
    const int* __restrict__ off, const u32* __restrict__ epack,
    const u16* __restrict__ inb, float (*zsh)[HID],
    u16* __restrict__ outb, float* __restrict__ outf)
{
    for (int i = 0; i < NPW; ++i) {
        const int nd = base + i;
        if (nd >= n) break;
        const int beg = off[nd];
        const int end = off[nd + 1];

        float ax = 0.f, ay = 0.f;
        for (int j = beg; j < end; j += 64) {
            int cnt = end - j; if (cnt > 64) cnt = 64;
            u32 e = 0;
            if (lane < cnt) e = epack[j + lane];

            int jj = 0;
            for (; jj + 8 <= cnt; jj += 8) {
                u32 ee[8], s[8];
                #pragma unroll
                for (int u = 0; u < 8; ++u) ee[u] = __shfl(e, jj + u);
                #pragma unroll
                for (int u = 0; u < 8; ++u)
                    s[u] = *(const u32*)(inb + (size_t)(ee[u] & 0xFFFFu) * HID + lane * 2);
                #pragma unroll
                for (int u = 0; u < 8; ++u) {
                    float vv = bfhi(ee[u]);
                    ax += vv * bflo(s[u]);
                    ay += vv * bfhi(s[u]);
                }
            }
            for (; jj + 4 <= cnt; jj += 4) {
                u32 ee[4], s[4];
                #pragma unroll
                for (int u = 0; u < 4; ++u) ee[u] = __shfl(e, jj + u);
                #pragma unroll
                for (int u = 0; u < 4; ++u)
                    s[u] = *(const u32*)(inb + (size_t)(ee[u] & 0xFFFFu) * HID + lane * 2);
                #pragma unroll
                for (int u = 0; u < 4; ++u) {
                    float vv = bfhi(ee[u]);
                    ax += vv * bflo(s[u]);
                    ay += vv * bfhi(s[u]);
                }
            }
            for (; jj < cnt; ++jj) {
                u32 ee = __shfl(e, jj);
                u32 s  = *(const u32*)(inb + (size_t)(ee & 0xFFFFu) * HID + lane * 2);
                float vv = bfhi(ee);
                ax += vv * bflo(s);
                ay += vv * bfhi(s);
            }
        }

        const float zx = zsh[i][lane * 2];
        const float zy = zsh[i][lane * 2 + 1];
        const float ox = 0.75f * zx + 0.25f * ax;
        const float oy = 0.75f * zy + 0.25f * ay;
        if (outb) {
            zsh[i][lane * 2]     = ox;
            zsh[i][lane * 2 + 1] = oy;
            u32 pb = (u32)f2bf(ox) | ((u32)f2bf(oy) << 16);
            *(u32*)(outb + (size_t)nd * HID + lane * 2) = pb;
        } else {
            float2 o; o.x = ox; o.y = oy;
            *(float2*)(outf + (size_t)nd * HID + lane * 2) = o;
        }
    }
}

// ---------------------------------------------------------------------------
// Fused 4-step Euler integration, cooperative launch (grid-wide sync).
// 1024 blocks x 256 thr, 4 blocks/CU co-resident (<=128 VGPR enforced).
// fp32 state in LDS for all steps: saves 51.2 MB/step of fp32 streaming.
// Distinct bf16 exchange buffers per step (xb->b1->b2->b3): no re-written
// buffer within the launch -> no stale-L2 hazard across XCDs.
// ---------------------------------------------------------------------------
__global__ __launch_bounds__(256, 4) void euler_coop(
    const float* __restrict__ x,
    const u16* __restrict__ xb, u16* __restrict__ b1,
    u16* __restrict__ b2, u16* __restrict__ b3,
    float* __restrict__ outf,
    const int* __restrict__ off, const u32* __restrict__ epack, int n)
{
    __shared__ float zsh[4][NPW][HID];    // 26.6 KB
    const int wv   = threadIdx.x >> 6;
    const int lane = threadIdx.x & 63;
    const int base = (blockIdx.x * 4 + wv) * NPW;

    // init fp32 state from x (each wave touches only its own LDS slice)
    for (int i = 0; i < NPW; ++i) {
        const int nd = base + i;
        if (nd >= n) break;
        float2 xi = *(const float2*)(x + (size_t)nd * HID + lane * 2);
        zsh[wv][i][lane * 2]     = xi.x;
        zsh[wv][i][lane * 2 + 1] = xi.y;
    }

    cg::grid_group grid = cg::this_grid();

    euler_step(lane, base, n, off, epack, xb, zsh[wv], b1, nullptr);
    __threadfence(); grid.sync();
    euler_step(lane, base, n, off, epack, b1, zsh[wv], b2, nullptr);
    __threadfence(); grid.sync();
    euler_step(lane, base, n, off, epack, b2, zsh[wv], b3, nullptr);
    __threadfence(); grid.sync();
    euler_step(lane, base, n, off, epack, b3, zsh[wv], nullptr, outf);
}

// ---------------------------------------------------------------------------
extern "C" void kernel_launch(void* const* d_in, const int* in_sizes, int n_in,
                              void* d_out, int out_size, void* d_ws, size_t ws_size,
                              hipStream_t stream)
{
    (void)in_sizes; (void)n_in; (void)out_size; (void)ws_size;

    const float* x  = (const float*)d_in[0];
    const float* Wq = (const float*)d_in[1];
    const float* bq = (const float*)d_in[2];
    const float* Wk = (const float*)d_in[3];
    const float* bk = (const float*)d_in[4];
    const int*   ei = (const int*)d_in[5];
    float* out = (float*)d_out;

    const int N = NODES, E = EDGES;
    const size_t ROWB_B = (size_t)N * HID * 2;   // 12.8 MB bf16 state

    char* ws = (char*)d_ws;
    // region A (25.6 MB): qb|kb -- dead after score -- reused as b1|b2
    u16*   qb    = (u16*)(ws);
    u16*   kb    = (u16*)(ws + ROWB_B);
    u16*   b1    = (u16*)(ws);
    u16*   b2    = (u16*)(ws + ROWB_B);
    ws += 2 * ROWB_B;
    // xb: bf16 copy of x, live through euler step 1
    u16*   xb    = (u16*)ws;  ws += ROWB_B;
    // evals -- dead after finalize -- reused as b3
    float* evals = (float*)ws;
    u16*   b3    = (u16*)ws;  ws += (size_t)E * HEADS * 4;   // 12.8 MB
    float* nsum  = (float*)ws; ws += (size_t)N * HEADS * 4;
    int*   deg   = (int*)ws;   ws += (size_t)N * 4;
    int*   off   = (int*)ws;   ws += ((size_t)(N + 1) * 4 + 255) & ~255ull;
    int*   bcur  = (int*)ws;   ws += ((size_t)NBUCK * 4 + 255) & ~255ull;
    int*   part  = (int*)ws;   ws += 256;
    u32*   epack = (u32*)ws;   ws += (size_t)E * 4;   // dst-only CSR, then packed
    u32*   tmp   = (u32*)ws;   ws += (size_t)E * 4;   // bucket-grouped edges
    u16*   Wqt   = (u16*)ws;   ws += (size_t)128 * 128 * 2;
    u16*   Wkt   = (u16*)ws;   ws += (size_t)128 * 128 * 2;

    // zero nsum + deg (contiguous)
    hipMemsetAsync(nsum, 0, (size_t)N * HEADS * 4 + (size_t)N * 4, stream);

    // W -> bf16 transposed
    wprep<<<128, 256, 0, stream>>>(Wq, Wk, Wqt, Wkt);

    // Q/K projections via MFMA (bf16 out) + row-major bf16 copy of x
    gemm_qk_mfma<<<(N + 63) / 64, 256, 0, stream>>>(
        x, Wqt, bq, Wkt, bk, qb, kb, xb, N);

    // degree histogram (by src)
    hist_kernel<<<E / 256, 256, 0, stream>>>(ei, deg);

    // CSR offsets: two-level scan (+ bucket cursors)
    const int nb = (N + 1023) / 1024;
    scan1<<<nb, 1024, 0, stream>>>(deg, off, part, N);
    scan2<<<1, 64, 0, stream>>>(part, off + N, nb);
    scan3<<<nb, 1024, 0, stream>>>(off, bcur, part, N);

    // two-phase binned CSR fill
    bin_edges<<<(E + CHUNK - 1) / CHUNK, 256, 0, stream>>>(ei, bcur, tmp);
    place_edges<<<NBUCK, 256, 0, stream>>>(tmp, off, epack, N);

    // CSR-ordered scores -> exp -> segment sums
    score_csr<<<(N * 64 + 255) / 256, 256, 0, stream>>>(
        qb, kb, off, epack, evals, nsum, N);

    // attention mean, packed in place
    finalize_kernel<<<E / 256, 256, 0, stream>>>(evals, nsum, epack);

    // fused 4-step Euler integration (cooperative, fp32 state in LDS)
    int Nv = N;
    void* args[] = { (void*)&x, (void*)&xb, (void*)&b1, (void*)&b2, (void*)&b3,
                     (void*)&out, (void*)&off, (void*)&epack, (void*)&Nv };
    hipLaunchCooperativeKernel((const void*)euler_coop, dim3(COOP_BLOCKS),
                               dim3(256), args, 0, stream);
}

// Round 8
// 292.008 us; speedup vs baseline: 3.4281x; 3.4281x over previous
//
#include <hip/hip_runtime.h>
#include <hip/hip_fp16.h>

#define NODES 50000
#define EDGES 800000
#define HID   128
#define HEADS 4
// DK = 32, scale = 1/sqrt(32)
#define SCORE_SCALE 0.17677669529663687f

#define NBUCK ((NODES + 255) >> 8)   // 196 buckets of 256 src nodes
#define CHUNK 4096

typedef unsigned int       u32;
typedef unsigned short     u16;
typedef unsigned long long u64;

typedef __attribute__((ext_vector_type(8))) short bf16x8;
typedef __attribute__((ext_vector_type(4))) float f32x4;

// round-to-nearest-even f32 -> bf16
__device__ __forceinline__ u16 f2bf(float f) {
    u32 u = __builtin_bit_cast(u32, f);
    return (u16)((u + 0x7FFFu + ((u >> 16) & 1u)) >> 16);
}
__device__ __forceinline__ float bflo(u32 u) { return __builtin_bit_cast(float, u << 16); }
__device__ __forceinline__ float bfhi(u32 u) { return __builtin_bit_cast(float, u & 0xFFFF0000u); }
__device__ __forceinline__ float bdot2(u32 a, u32 b) {
    return bflo(a) * bflo(b) + bfhi(a) * bfhi(b);
}
// fp16 pair <-> f32 pair
__device__ __forceinline__ float2 h2f2(u32 u) {
    __half2 h = __builtin_bit_cast(__half2, u);
    return __half22float2(h);
}
__device__ __forceinline__ u32 f2h2(float a, float b) {
    __half2 h = __floats2half2_rn(a, b);
    return __builtin_bit_cast(u32, h);
}

// ---------------------------------------------------------------------------
// W prep: Wt[n][k] = bf16(W[k][n]), both 128x128. 2 matrices.
// ---------------------------------------------------------------------------
__global__ __launch_bounds__(256) void wprep(
    const float* __restrict__ Wq, const float* __restrict__ Wk,
    u16* __restrict__ Wqt, u16* __restrict__ Wkt)
{
    int e   = blockIdx.x * 256 + threadIdx.x;
    int mat = e >> 14;
    int idx = e & 16383;
    int k  = idx >> 7;
    int nn = idx & 127;
    const float* W = mat ? Wk : Wq;
    u16*        Wt = mat ? Wkt : Wqt;
    Wt[nn * 128 + k] = f2bf(W[idx]);
}

// ---------------------------------------------------------------------------
// MFMA Q/K projection. Wave = one 16-row tile, both matrices.
// Also emits row-major fp16 copy of x (xh) for the Euler gathers.
// ---------------------------------------------------------------------------
__global__ __launch_bounds__(256) void gemm_qk_mfma(
    const float* __restrict__ x,
    const u16* __restrict__ Wqt, const float* __restrict__ bq,
    const u16* __restrict__ Wkt, const float* __restrict__ bk,
    u16* __restrict__ qb, u16* __restrict__ kb, u16* __restrict__ xh, int n)
{
    const int l  = threadIdx.x & 63;
    const int w  = threadIdx.x >> 6;
    const int lr = l & 15;
    const int kg = l >> 4;

    const int arow   = blockIdx.x * 64 + w * 16 + lr;
    const bool av    = (arow < n);
    const int  arowc = av ? arow : (n - 1);

    bf16x8 afrag[4];
    #pragma unroll
    for (int ks = 0; ks < 4; ++ks) {
        const float* px = x + (size_t)arowc * HID + ks * 32 + kg * 8;
        float4 p0 = *(const float4*)px;
        float4 p1 = *(const float4*)(px + 4);
        uint4 pk;
        pk.x = (u32)f2bf(p0.x) | ((u32)f2bf(p0.y) << 16);
        pk.y = (u32)f2bf(p0.z) | ((u32)f2bf(p0.w) << 16);
        pk.z = (u32)f2bf(p1.x) | ((u32)f2bf(p1.y) << 16);
        pk.w = (u32)f2bf(p1.z) | ((u32)f2bf(p1.w) << 16);
        afrag[ks] = __builtin_bit_cast(bf16x8, pk);
        if (av) {
            uint4 ph;
            ph.x = f2h2(p0.x, p0.y);
            ph.y = f2h2(p0.z, p0.w);
            ph.z = f2h2(p1.x, p1.y);
            ph.w = f2h2(p1.z, p1.w);
            *(uint4*)(xh + (size_t)arow * HID + ks * 32 + kg * 8) = ph;
        }
    }

    #pragma unroll
    for (int mat = 0; mat < 2; ++mat) {
        const u16*   Wt   = mat ? Wkt : Wqt;
        const float* bias = mat ? bk : bq;
        u16*         outp = mat ? kb : qb;

        #pragma unroll
        for (int cb = 0; cb < 8; ++cb) {
            float bc = bias[cb * 16 + lr];
            f32x4 acc = {bc, bc, bc, bc};
            #pragma unroll
            for (int ks = 0; ks < 4; ++ks) {
                bf16x8 bfrag = __builtin_bit_cast(bf16x8,
                    *(const uint4*)(Wt + (size_t)(cb * 16 + lr) * 128 + ks * 32 + kg * 8));
                acc = __builtin_amdgcn_mfma_f32_16x16x32_bf16(afrag[ks], bfrag, acc, 0, 0, 0);
            }
            #pragma unroll
            for (int reg = 0; reg < 4; ++reg) {
                int gr = blockIdx.x * 64 + w * 16 + kg * 4 + reg;
                if (gr < n) outp[(size_t)gr * HID + cb * 16 + lr] = f2bf(acc[reg]);
            }
        }
    }
}

// ---------------------------------------------------------------------------
// out-degree histogram over src
// ---------------------------------------------------------------------------
__global__ __launch_bounds__(256) void hist_kernel(
    const int* __restrict__ ei, int* __restrict__ deg)
{
    int i = blockIdx.x * 256 + threadIdx.x;
    if (i < EDGES) atomicAdd(&deg[ei[i]], 1);
}

// ---------------------------------------------------------------------------
// two-level exclusive scan of deg -> off; also emits bucket cursors
// ---------------------------------------------------------------------------
__global__ __launch_bounds__(1024) void scan1(
    const int* __restrict__ deg, int* __restrict__ off,
    int* __restrict__ part, int n)
{
    __shared__ int sd[1024];
    int t = threadIdx.x, i = blockIdx.x * 1024 + t;
    int v = (i < n) ? deg[i] : 0;
    sd[t] = v;
    __syncthreads();
    #pragma unroll
    for (int o = 1; o < 1024; o <<= 1) {
        int a = (t >= o) ? sd[t - o] : 0;
        __syncthreads();
        sd[t] += a;
        __syncthreads();
    }
    if (i < n) off[i] = sd[t] - v;
    if (t == 1023) part[blockIdx.x] = sd[1023];
}

__global__ __launch_bounds__(64) void scan2(int* __restrict__ part,
                                            int* __restrict__ off_n, int nb)
{
    int t = threadIdx.x;
    int v = (t < nb) ? part[t] : 0;
    int orig = v;
    #pragma unroll
    for (int o = 1; o < 64; o <<= 1) {
        int a = __shfl_up(v, o);
        if (t >= o) v += a;
    }
    if (t < nb) part[t] = v - orig;
    if (t == 63) *off_n = v;
}

__global__ __launch_bounds__(1024) void scan3(
    int* __restrict__ off, int* __restrict__ bcur,
    const int* __restrict__ part, int n)
{
    int i = blockIdx.x * 1024 + threadIdx.x;
    if (i < n) {
        int o = off[i] + part[blockIdx.x];
        off[i] = o;
        if ((i & 255) == 0) bcur[i >> 8] = o;   // bucket base cursor
    }
}

// ---------------------------------------------------------------------------
// Phase 1: bin edges by bucket (src>>8) into tmp, bucket-contiguous.
// ---------------------------------------------------------------------------
__global__ __launch_bounds__(256) void bin_edges(
    const int* __restrict__ ei, int* __restrict__ bcur, u32* __restrict__ tmp)
{
    __shared__ u32 buf[CHUNK];
    __shared__ int hist[NBUCK];
    __shared__ int lcur[NBUCK];

    const int t  = threadIdx.x;
    const int e0 = blockIdx.x * CHUNK;
    const int e1 = (e0 + CHUNK < EDGES) ? e0 + CHUNK : EDGES;
    const int cnt = e1 - e0;

    for (int b = t; b < NBUCK; b += 256) hist[b] = 0;
    __syncthreads();

    for (int i = t; i < cnt; i += 256) {
        int src = ei[e0 + i];
        int dst = ei[EDGES + e0 + i];
        buf[i] = (u32)dst | ((u32)(src & 255) << 16) | ((u32)(src >> 8) << 24);
        atomicAdd(&hist[src >> 8], 1);
    }
    __syncthreads();

    for (int b = t; b < NBUCK; b += 256) {
        int h = hist[b];
        lcur[b] = h ? atomicAdd(&bcur[b], h) : 0;
    }
    __syncthreads();

    for (int i = t; i < cnt; i += 256) {
        u32 pk  = buf[i];
        int b   = pk >> 24;
        int pos = atomicAdd(&lcur[b], 1);
        tmp[pos] = pk & 0x00FFFFFFu;          // srcLocal<<16 | dst
    }
}

// ---------------------------------------------------------------------------
// Phase 2: exact CSR placement within each bucket (LDS cursors, local window)
// ---------------------------------------------------------------------------
__global__ __launch_bounds__(256) void place_edges(
    const u32* __restrict__ tmp, const int* __restrict__ off,
    u32* __restrict__ epack, int n)
{
    __shared__ int lcur[256];
    const int t     = threadIdx.x;
    const int nbase = blockIdx.x << 8;
    const int nend  = (nbase + 256 < n) ? nbase + 256 : n;

    if (nbase + t < nend) lcur[t] = off[nbase + t];
    __syncthreads();

    const int s0 = off[nbase];
    const int s1 = off[nend];
    for (int i = s0 + t; i < s1; i += 256) {
        u32 pk    = tmp[i];
        int local = pk >> 16;
        int pos   = atomicAdd(&lcur[local], 1);
        epack[pos] = pk & 0xFFFFu;            // dst only (att packed later)
    }
}

// ---------------------------------------------------------------------------
// CSR-ordered scores: wave per src node. q[src] loaded ONCE (sequential),
// only k[dst] gathered randomly.
// ---------------------------------------------------------------------------
__global__ __launch_bounds__(256) void score_csr(
    const u16* __restrict__ qb, const u16* __restrict__ kb,
    const int* __restrict__ off, const u32* __restrict__ ccol,
    float* __restrict__ evals, float* __restrict__ nsum, int n)
{
    const int wv   = (blockIdx.x * 256 + threadIdx.x) >> 6;   // src node
    const int lane = threadIdx.x & 63;
    const int l16  = lane & 15;
    const int grp  = lane >> 4;
    if (wv >= n) return;

    const int beg = off[wv];
    const int end = off[wv + 1];

    uint4 qv = *(const uint4*)(qb + (size_t)wv * HID + l16 * 8);

    #pragma unroll 2
    for (int j = beg; j < end; j += 4) {
        int e = j + grp;
        if (e < end) {
            u32 dst = ccol[e];
            uint4 kv = *(const uint4*)(kb + (size_t)dst * HID + l16 * 8);
            float p = bdot2(qv.x, kv.x) + bdot2(qv.y, kv.y) +
                      bdot2(qv.z, kv.z) + bdot2(qv.w, kv.w);
            p += __shfl_xor(p, 1);
            p += __shfl_xor(p, 2);
            if ((l16 & 3) == 0) {
                int head = l16 >> 2;
                float ev = __expf(p * SCORE_SCALE);
                evals[(size_t)e * HEADS + head] = ev;
                atomicAdd(&nsum[(size_t)dst * HEADS + head], ev);
            }
        }
    }
}

// ---------------------------------------------------------------------------
// head-mean attention; packs epack[pos] = dst | bf16(att)<<16 IN PLACE.
// ---------------------------------------------------------------------------
__global__ __launch_bounds__(256) void finalize_kernel(
    const float* __restrict__ evals, const float* __restrict__ nsum,
    u32* __restrict__ epack)
{
    int pos = blockIdx.x * 256 + threadIdx.x;
    if (pos >= EDGES) return;
    u32 dst = epack[pos];
    float4 ev = *(const float4*)(evals + (size_t)pos * HEADS);
    float4 sv = *(const float4*)(nsum  + (size_t)dst * HEADS);
    float am = 0.25f * (ev.x / (sv.x + 1e-16f) + ev.y / (sv.y + 1e-16f) +
                        ev.z / (sv.z + 1e-16f) + ev.w / (sv.w + 1e-16f));
    epack[pos] = dst | ((u32)f2bf(am) << 16);
}

// ---------------------------------------------------------------------------
// Euler step, fp16 state: out[i,:] = 0.75*in[i,:] + 0.25*sum att[j]*in[dst,:]
// Single fp16 buffer per step (state + gather source); final step writes f32.
// Wave per node; 8-deep batched gathers to keep L3 latency covered.
// NOTE (r7 post-mortem): do NOT trade wave count for LDS residency here --
// the coop-fused variant starved outstanding requests (463 GB/s, VALU 6.8%).
// ---------------------------------------------------------------------------
template<int FINAL>
__global__ __launch_bounds__(256) void spmv_h(
    const u16* __restrict__ inh, u16* __restrict__ outh,
    float* __restrict__ outf,
    const int* __restrict__ off, const u32* __restrict__ epack, int n)
{
    const int w    = (blockIdx.x * 256 + threadIdx.x) >> 6;
    const int lane = threadIdx.x & 63;
    if (w >= n) return;

    const int beg = off[w];
    const int end = off[w + 1];

    float ax = 0.f, ay = 0.f;
    for (int j = beg; j < end; j += 64) {
        int cnt = end - j; if (cnt > 64) cnt = 64;
        u32 e = 0;
        if (lane < cnt) e = epack[j + lane];

        int jj = 0;
        for (; jj + 8 <= cnt; jj += 8) {
            u32 ee[8], s[8];
            #pragma unroll
            for (int u = 0; u < 8; ++u) ee[u] = __shfl(e, jj + u);
            #pragma unroll
            for (int u = 0; u < 8; ++u)
                s[u] = *(const u32*)(inh + (size_t)(ee[u] & 0xFFFFu) * HID + lane * 2);
            #pragma unroll
            for (int u = 0; u < 8; ++u) {
                float vv = bfhi(ee[u]);
                float2 sv = h2f2(s[u]);
                ax += vv * sv.x;
                ay += vv * sv.y;
            }
        }
        for (; jj + 4 <= cnt; jj += 4) {
            u32 ee[4], s[4];
            #pragma unroll
            for (int u = 0; u < 4; ++u) ee[u] = __shfl(e, jj + u);
            #pragma unroll
            for (int u = 0; u < 4; ++u)
                s[u] = *(const u32*)(inh + (size_t)(ee[u] & 0xFFFFu) * HID + lane * 2);
            #pragma unroll
            for (int u = 0; u < 4; ++u) {
                float vv = bfhi(ee[u]);
                float2 sv = h2f2(s[u]);
                ax += vv * sv.x;
                ay += vv * sv.y;
            }
        }
        for (; jj < cnt; ++jj) {
            u32 ee = __shfl(e, jj);
            u32 s  = *(const u32*)(inh + (size_t)(ee & 0xFFFFu) * HID + lane * 2);
            float vv = bfhi(ee);
            float2 sv = h2f2(s);
            ax += vv * sv.x;
            ay += vv * sv.y;
        }
    }

    u32 zi = *(const u32*)(inh + (size_t)w * HID + lane * 2);
    float2 xi = h2f2(zi);
    const float ox = 0.75f * xi.x + 0.25f * ax;
    const float oy = 0.75f * xi.y + 0.25f * ay;
    if (FINAL) {
        float2 o; o.x = ox; o.y = oy;
        *(float2*)(outf + (size_t)w * HID + lane * 2) = o;
    } else {
        *(u32*)(outh + (size_t)w * HID + lane * 2) = f2h2(ox, oy);
    }
}

// ---------------------------------------------------------------------------
extern "C" void kernel_launch(void* const* d_in, const int* in_sizes, int n_in,
                              void* d_out, int out_size, void* d_ws, size_t ws_size,
                              hipStream_t stream)
{
    (void)in_sizes; (void)n_in; (void)out_size; (void)ws_size;

    const float* x  = (const float*)d_in[0];
    const float* Wq = (const float*)d_in[1];
    const float* bq = (const float*)d_in[2];
    const float* Wk = (const float*)d_in[3];
    const float* bk = (const float*)d_in[4];
    const int*   ei = (const int*)d_in[5];
    float* out = (float*)d_out;

    const int N = NODES, E = EDGES;
    const size_t ROWB_B = (size_t)N * HID * 2;   // 12.8 MB 16-bit state

    char* ws = (char*)d_ws;
    // region A (25.6 MB): qb|kb -- dead after score_csr -- reused as z1|z2
    u16*   qb    = (u16*)(ws);
    u16*   kb    = (u16*)(ws + ROWB_B);
    u16*   z1    = (u16*)(ws);
    u16*   z2    = (u16*)(ws + ROWB_B);
    ws += 2 * ROWB_B;
    // xh: fp16 copy of x, live through euler step 1
    u16*   xh    = (u16*)ws;  ws += ROWB_B;
    // evals (12.8 MB) -- dead after finalize -- reused as z3
    float* evals = (float*)ws;
    u16*   z3    = (u16*)ws;  ws += (size_t)E * HEADS * 4;
    float* nsum  = (float*)ws; ws += (size_t)N * HEADS * 4;
    int*   deg   = (int*)ws;   ws += (size_t)N * 4;
    int*   off   = (int*)ws;   ws += ((size_t)(N + 1) * 4 + 255) & ~255ull;
    int*   bcur  = (int*)ws;   ws += ((size_t)NBUCK * 4 + 255) & ~255ull;
    int*   part  = (int*)ws;   ws += 256;
    u32*   epack = (u32*)ws;   ws += (size_t)E * 4;   // dst-only CSR, then packed
    u32*   tmp   = (u32*)ws;   ws += (size_t)E * 4;   // bucket-grouped edges
    u16*   Wqt   = (u16*)ws;   ws += (size_t)128 * 128 * 2;
    u16*   Wkt   = (u16*)ws;   ws += (size_t)128 * 128 * 2;

    // zero nsum + deg (contiguous)
    hipMemsetAsync(nsum, 0, (size_t)N * HEADS * 4 + (size_t)N * 4, stream);

    // W -> bf16 transposed
    wprep<<<128, 256, 0, stream>>>(Wq, Wk, Wqt, Wkt);

    // Q/K projections via MFMA (bf16 out) + fp16 copy of x
    gemm_qk_mfma<<<(N + 63) / 64, 256, 0, stream>>>(
        x, Wqt, bq, Wkt, bk, qb, kb, xh, N);

    // degree histogram (by src)
    hist_kernel<<<E / 256, 256, 0, stream>>>(ei, deg);

    // CSR offsets: two-level scan (+ bucket cursors)
    const int nb = (N + 1023) / 1024;
    scan1<<<nb, 1024, 0, stream>>>(deg, off, part, N);
    scan2<<<1, 64, 0, stream>>>(part, off + N, nb);
    scan3<<<nb, 1024, 0, stream>>>(off, bcur, part, N);

    // two-phase binned CSR fill
    bin_edges<<<(E + CHUNK - 1) / CHUNK, 256, 0, stream>>>(ei, bcur, tmp);
    place_edges<<<NBUCK, 256, 0, stream>>>(tmp, off, epack, N);

    // CSR-ordered scores -> exp -> segment sums
    score_csr<<<(N * 64 + 255) / 256, 256, 0, stream>>>(
        qb, kb, off, epack, evals, nsum, N);

    // attention mean, packed in place
    finalize_kernel<<<E / 256, 256, 0, stream>>>(evals, nsum, epack);

    // 4 Euler steps, fp16 state chain: xh -> z1 -> z2 -> z3 -> out(fp32)
    const int sg = (N * 64 + 255) / 256;
    spmv_h<0><<<sg, 256, 0, stream>>>(xh, z1, nullptr, off, epack, N);
    spmv_h<0><<<sg, 256, 0, stream>>>(z1, z2, nullptr, off, epack, N);
    spmv_h<0><<<sg, 256, 0, stream>>>(z2, z3, nullptr, off, epack, N);
    spmv_h<1><<<sg, 256, 0, stream>>>(z3, nullptr, out, off, epack, N);
}

// Round 9
// 290.190 us; speedup vs baseline: 3.4495x; 1.0063x over previous
//
#include <hip/hip_runtime.h>
#include <hip/hip_fp16.h>

#define NODES 50000
#define EDGES 800000
#define HID   128
#define HEADS 4
// DK = 32, scale = 1/sqrt(32)
#define SCORE_SCALE 0.17677669529663687f

#define NBUCK ((NODES + 255) >> 8)   // 196 buckets of 256 src nodes
#define CHUNK 4096

typedef unsigned int       u32;
typedef unsigned short     u16;
typedef unsigned long long u64;

typedef __attribute__((ext_vector_type(8))) short bf16x8;
typedef __attribute__((ext_vector_type(4))) float f32x4;

// round-to-nearest-even f32 -> bf16
__device__ __forceinline__ u16 f2bf(float f) {
    u32 u = __builtin_bit_cast(u32, f);
    return (u16)((u + 0x7FFFu + ((u >> 16) & 1u)) >> 16);
}
__device__ __forceinline__ float bflo(u32 u) { return __builtin_bit_cast(float, u << 16); }
__device__ __forceinline__ float bfhi(u32 u) { return __builtin_bit_cast(float, u & 0xFFFF0000u); }
__device__ __forceinline__ float bdot2(u32 a, u32 b) {
    return bflo(a) * bflo(b) + bfhi(a) * bfhi(b);
}
// fp16 pair <-> f32 pair
__device__ __forceinline__ float2 h2f2(u32 u) {
    __half2 h = __builtin_bit_cast(__half2, u);
    return __half22float2(h);
}
__device__ __forceinline__ u32 f2h2(float a, float b) {
    __half2 h = __floats2half2_rn(a, b);
    return __builtin_bit_cast(u32, h);
}

// ---------------------------------------------------------------------------
// W prep: Wt[n][k] = bf16(W[k][n]), both 128x128. 2 matrices.
// ---------------------------------------------------------------------------
__global__ __launch_bounds__(256) void wprep(
    const float* __restrict__ Wq, const float* __restrict__ Wk,
    u16* __restrict__ Wqt, u16* __restrict__ Wkt)
{
    int e   = blockIdx.x * 256 + threadIdx.x;
    int mat = e >> 14;
    int idx = e & 16383;
    int k  = idx >> 7;
    int nn = idx & 127;
    const float* W = mat ? Wk : Wq;
    u16*        Wt = mat ? Wkt : Wqt;
    Wt[nn * 128 + k] = f2bf(W[idx]);
}

// ---------------------------------------------------------------------------
// MFMA Q/K projection. Wave = one 16-row tile, both matrices.
// Also emits row-major fp16 copy of x (xh) for the Euler gathers.
// ---------------------------------------------------------------------------
__global__ __launch_bounds__(256) void gemm_qk_mfma(
    const float* __restrict__ x,
    const u16* __restrict__ Wqt, const float* __restrict__ bq,
    const u16* __restrict__ Wkt, const float* __restrict__ bk,
    u16* __restrict__ qb, u16* __restrict__ kb, u16* __restrict__ xh, int n)
{
    const int l  = threadIdx.x & 63;
    const int w  = threadIdx.x >> 6;
    const int lr = l & 15;
    const int kg = l >> 4;

    const int arow   = blockIdx.x * 64 + w * 16 + lr;
    const bool av    = (arow < n);
    const int  arowc = av ? arow : (n - 1);

    bf16x8 afrag[4];
    #pragma unroll
    for (int ks = 0; ks < 4; ++ks) {
        const float* px = x + (size_t)arowc * HID + ks * 32 + kg * 8;
        float4 p0 = *(const float4*)px;
        float4 p1 = *(const float4*)(px + 4);
        uint4 pk;
        pk.x = (u32)f2bf(p0.x) | ((u32)f2bf(p0.y) << 16);
        pk.y = (u32)f2bf(p0.z) | ((u32)f2bf(p0.w) << 16);
        pk.z = (u32)f2bf(p1.x) | ((u32)f2bf(p1.y) << 16);
        pk.w = (u32)f2bf(p1.z) | ((u32)f2bf(p1.w) << 16);
        afrag[ks] = __builtin_bit_cast(bf16x8, pk);
        if (av) {
            uint4 ph;
            ph.x = f2h2(p0.x, p0.y);
            ph.y = f2h2(p0.z, p0.w);
            ph.z = f2h2(p1.x, p1.y);
            ph.w = f2h2(p1.z, p1.w);
            *(uint4*)(xh + (size_t)arow * HID + ks * 32 + kg * 8) = ph;
        }
    }

    #pragma unroll
    for (int mat = 0; mat < 2; ++mat) {
        const u16*   Wt   = mat ? Wkt : Wqt;
        const float* bias = mat ? bk : bq;
        u16*         outp = mat ? kb : qb;

        #pragma unroll
        for (int cb = 0; cb < 8; ++cb) {
            float bc = bias[cb * 16 + lr];
            f32x4 acc = {bc, bc, bc, bc};
            #pragma unroll
            for (int ks = 0; ks < 4; ++ks) {
                bf16x8 bfrag = __builtin_bit_cast(bf16x8,
                    *(const uint4*)(Wt + (size_t)(cb * 16 + lr) * 128 + ks * 32 + kg * 8));
                acc = __builtin_amdgcn_mfma_f32_16x16x32_bf16(afrag[ks], bfrag, acc, 0, 0, 0);
            }
            #pragma unroll
            for (int reg = 0; reg < 4; ++reg) {
                int gr = blockIdx.x * 64 + w * 16 + kg * 4 + reg;
                if (gr < n) outp[(size_t)gr * HID + cb * 16 + lr] = f2bf(acc[reg]);
            }
        }
    }
}

// ---------------------------------------------------------------------------
// out-degree histogram over src
// ---------------------------------------------------------------------------
__global__ __launch_bounds__(256) void hist_kernel(
    const int* __restrict__ ei, int* __restrict__ deg)
{
    int i = blockIdx.x * 256 + threadIdx.x;
    if (i < EDGES) atomicAdd(&deg[ei[i]], 1);
}

// ---------------------------------------------------------------------------
// two-level exclusive scan of deg -> off; also emits bucket cursors
// ---------------------------------------------------------------------------
__global__ __launch_bounds__(1024) void scan1(
    const int* __restrict__ deg, int* __restrict__ off,
    int* __restrict__ part, int n)
{
    __shared__ int sd[1024];
    int t = threadIdx.x, i = blockIdx.x * 1024 + t;
    int v = (i < n) ? deg[i] : 0;
    sd[t] = v;
    __syncthreads();
    #pragma unroll
    for (int o = 1; o < 1024; o <<= 1) {
        int a = (t >= o) ? sd[t - o] : 0;
        __syncthreads();
        sd[t] += a;
        __syncthreads();
    }
    if (i < n) off[i] = sd[t] - v;
    if (t == 1023) part[blockIdx.x] = sd[1023];
}

__global__ __launch_bounds__(64) void scan2(int* __restrict__ part,
                                            int* __restrict__ off_n, int nb)
{
    int t = threadIdx.x;
    int v = (t < nb) ? part[t] : 0;
    int orig = v;
    #pragma unroll
    for (int o = 1; o < 64; o <<= 1) {
        int a = __shfl_up(v, o);
        if (t >= o) v += a;
    }
    if (t < nb) part[t] = v - orig;
    if (t == 63) *off_n = v;
}

__global__ __launch_bounds__(1024) void scan3(
    int* __restrict__ off, int* __restrict__ bcur,
    const int* __restrict__ part, int n)
{
    int i = blockIdx.x * 1024 + threadIdx.x;
    if (i < n) {
        int o = off[i] + part[blockIdx.x];
        off[i] = o;
        if ((i & 255) == 0) bcur[i >> 8] = o;   // bucket base cursor
    }
}

// ---------------------------------------------------------------------------
// Phase 1: bin edges by bucket (src>>8) into tmp, bucket-contiguous.
// ---------------------------------------------------------------------------
__global__ __launch_bounds__(256) void bin_edges(
    const int* __restrict__ ei, int* __restrict__ bcur, u32* __restrict__ tmp)
{
    __shared__ u32 buf[CHUNK];
    __shared__ int hist[NBUCK];
    __shared__ int lcur[NBUCK];

    const int t  = threadIdx.x;
    const int e0 = blockIdx.x * CHUNK;
    const int e1 = (e0 + CHUNK < EDGES) ? e0 + CHUNK : EDGES;
    const int cnt = e1 - e0;

    for (int b = t; b < NBUCK; b += 256) hist[b] = 0;
    __syncthreads();

    for (int i = t; i < cnt; i += 256) {
        int src = ei[e0 + i];
        int dst = ei[EDGES + e0 + i];
        buf[i] = (u32)dst | ((u32)(src & 255) << 16) | ((u32)(src >> 8) << 24);
        atomicAdd(&hist[src >> 8], 1);
    }
    __syncthreads();

    for (int b = t; b < NBUCK; b += 256) {
        int h = hist[b];
        lcur[b] = h ? atomicAdd(&bcur[b], h) : 0;
    }
    __syncthreads();

    for (int i = t; i < cnt; i += 256) {
        u32 pk  = buf[i];
        int b   = pk >> 24;
        int pos = atomicAdd(&lcur[b], 1);
        tmp[pos] = pk & 0x00FFFFFFu;          // srcLocal<<16 | dst
    }
}

// ---------------------------------------------------------------------------
// Phase 2: exact CSR placement within each bucket (LDS cursors, local window)
// ---------------------------------------------------------------------------
__global__ __launch_bounds__(256) void place_edges(
    const u32* __restrict__ tmp, const int* __restrict__ off,
    u32* __restrict__ epack, int n)
{
    __shared__ int lcur[256];
    const int t     = threadIdx.x;
    const int nbase = blockIdx.x << 8;
    const int nend  = (nbase + 256 < n) ? nbase + 256 : n;

    if (nbase + t < nend) lcur[t] = off[nbase + t];
    __syncthreads();

    const int s0 = off[nbase];
    const int s1 = off[nend];
    for (int i = s0 + t; i < s1; i += 256) {
        u32 pk    = tmp[i];
        int local = pk >> 16;
        int pos   = atomicAdd(&lcur[local], 1);
        epack[pos] = pk & 0xFFFFu;            // dst only (att packed later)
    }
}

// ---------------------------------------------------------------------------
// CSR-ordered scores: wave per src node, 4 groups x 16 lanes, 4-deep gather
// pipelining per group (16 k-rows in flight per wave). q[src] loaded once.
// e-values stored as packed bf16 (2B per edge-head).
// ---------------------------------------------------------------------------
__global__ __launch_bounds__(256) void score_csr(
    const u16* __restrict__ qb, const u16* __restrict__ kb,
    const int* __restrict__ off, const u32* __restrict__ ccol,
    u16* __restrict__ evals16, float* __restrict__ nsum, int n)
{
    const int wv   = (blockIdx.x * 256 + threadIdx.x) >> 6;   // src node
    const int lane = threadIdx.x & 63;
    const int l16  = lane & 15;
    const int grp  = lane >> 4;
    if (wv >= n) return;

    const int beg = off[wv];
    const int end = off[wv + 1];

    uint4 qv = *(const uint4*)(qb + (size_t)wv * HID + l16 * 8);

    for (int j = beg; j < end; j += 16) {
        u32 d[4]; uint4 kv[4];
        #pragma unroll
        for (int u = 0; u < 4; ++u) {
            int e  = j + grp + u * 4;
            int ec = (e < end) ? e : (end - 1);
            d[u] = ccol[ec];
        }
        #pragma unroll
        for (int u = 0; u < 4; ++u)
            kv[u] = *(const uint4*)(kb + (size_t)d[u] * HID + l16 * 8);
        #pragma unroll
        for (int u = 0; u < 4; ++u) {
            int e = j + grp + u * 4;
            float p = bdot2(qv.x, kv[u].x) + bdot2(qv.y, kv[u].y) +
                      bdot2(qv.z, kv[u].z) + bdot2(qv.w, kv[u].w);
            p += __shfl_xor(p, 1);
            p += __shfl_xor(p, 2);
            if (e < end && (l16 & 3) == 0) {
                int head = l16 >> 2;
                float ev = __expf(p * SCORE_SCALE);
                evals16[(size_t)e * HEADS + head] = f2bf(ev);
                atomicAdd(&nsum[(size_t)d[u] * HEADS + head], ev);
            }
        }
    }
}

// ---------------------------------------------------------------------------
// head-mean attention; packs epack[pos] = dst | bf16(att)<<16 IN PLACE.
// Reads packed bf16 e-values (8B per edge).
// ---------------------------------------------------------------------------
__global__ __launch_bounds__(256) void finalize_kernel(
    const u16* __restrict__ evals16, const float* __restrict__ nsum,
    u32* __restrict__ epack)
{
    int pos = blockIdx.x * 256 + threadIdx.x;
    if (pos >= EDGES) return;
    u32 dst = epack[pos];
    u64 ev8 = *(const u64*)(evals16 + (size_t)pos * HEADS);
    u32 lo = (u32)ev8, hi = (u32)(ev8 >> 32);
    float4 sv = *(const float4*)(nsum + (size_t)dst * HEADS);
    float am = 0.25f * (bflo(lo) / (sv.x + 1e-16f) + bfhi(lo) / (sv.y + 1e-16f) +
                        bflo(hi) / (sv.z + 1e-16f) + bfhi(hi) / (sv.w + 1e-16f));
    epack[pos] = dst | ((u32)f2bf(am) << 16);
}

// ---------------------------------------------------------------------------
// Euler step, fp16 state: out[i,:] = 0.75*in[i,:] + 0.25*sum att[j]*in[dst,:]
// Single fp16 buffer per step; final step writes f32 out.
// Wave per node; 8-deep batched gathers to keep L3 latency covered.
// NOTE (r7 post-mortem): do NOT trade wave count for LDS residency here --
// the coop-fused variant starved outstanding requests (463 GB/s, VALU 6.8%).
// ---------------------------------------------------------------------------
template<int FINAL>
__global__ __launch_bounds__(256) void spmv_h(
    const u16* __restrict__ inh, u16* __restrict__ outh,
    float* __restrict__ outf,
    const int* __restrict__ off, const u32* __restrict__ epack, int n)
{
    const int w    = (blockIdx.x * 256 + threadIdx.x) >> 6;
    const int lane = threadIdx.x & 63;
    if (w >= n) return;

    const int beg = off[w];
    const int end = off[w + 1];

    float ax = 0.f, ay = 0.f;
    for (int j = beg; j < end; j += 64) {
        int cnt = end - j; if (cnt > 64) cnt = 64;
        u32 e = 0;
        if (lane < cnt) e = epack[j + lane];

        int jj = 0;
        for (; jj + 8 <= cnt; jj += 8) {
            u32 ee[8], s[8];
            #pragma unroll
            for (int u = 0; u < 8; ++u) ee[u] = __shfl(e, jj + u);
            #pragma unroll
            for (int u = 0; u < 8; ++u)
                s[u] = *(const u32*)(inh + (size_t)(ee[u] & 0xFFFFu) * HID + lane * 2);
            #pragma unroll
            for (int u = 0; u < 8; ++u) {
                float vv = bfhi(ee[u]);
                float2 sv = h2f2(s[u]);
                ax += vv * sv.x;
                ay += vv * sv.y;
            }
        }
        for (; jj + 4 <= cnt; jj += 4) {
            u32 ee[4], s[4];
            #pragma unroll
            for (int u = 0; u < 4; ++u) ee[u] = __shfl(e, jj + u);
            #pragma unroll
            for (int u = 0; u < 4; ++u)
                s[u] = *(const u32*)(inh + (size_t)(ee[u] & 0xFFFFu) * HID + lane * 2);
            #pragma unroll
            for (int u = 0; u < 4; ++u) {
                float vv = bfhi(ee[u]);
                float2 sv = h2f2(s[u]);
                ax += vv * sv.x;
                ay += vv * sv.y;
            }
        }
        for (; jj < cnt; ++jj) {
            u32 ee = __shfl(e, jj);
            u32 s  = *(const u32*)(inh + (size_t)(ee & 0xFFFFu) * HID + lane * 2);
            float vv = bfhi(ee);
            float2 sv = h2f2(s);
            ax += vv * sv.x;
            ay += vv * sv.y;
        }
    }

    u32 zi = *(const u32*)(inh + (size_t)w * HID + lane * 2);
    float2 xi = h2f2(zi);
    const float ox = 0.75f * xi.x + 0.25f * ax;
    const float oy = 0.75f * xi.y + 0.25f * ay;
    if (FINAL) {
        float2 o; o.x = ox; o.y = oy;
        *(float2*)(outf + (size_t)w * HID + lane * 2) = o;
    } else {
        *(u32*)(outh + (size_t)w * HID + lane * 2) = f2h2(ox, oy);
    }
}

// ---------------------------------------------------------------------------
extern "C" void kernel_launch(void* const* d_in, const int* in_sizes, int n_in,
                              void* d_out, int out_size, void* d_ws, size_t ws_size,
                              hipStream_t stream)
{
    (void)in_sizes; (void)n_in; (void)out_size; (void)ws_size;

    const float* x  = (const float*)d_in[0];
    const float* Wq = (const float*)d_in[1];
    const float* bq = (const float*)d_in[2];
    const float* Wk = (const float*)d_in[3];
    const float* bk = (const float*)d_in[4];
    const int*   ei = (const int*)d_in[5];
    float* out = (float*)d_out;

    const int N = NODES, E = EDGES;
    const size_t ROWB_B = (size_t)N * HID * 2;   // 12.8 MB 16-bit state

    char* ws = (char*)d_ws;
    // region A (25.6 MB): qb|kb -- dead after score_csr -- reused as z1|z2
    u16*   qb    = (u16*)(ws);
    u16*   kb    = (u16*)(ws + ROWB_B);
    u16*   z1    = (u16*)(ws);
    u16*   z2    = (u16*)(ws + ROWB_B);
    ws += 2 * ROWB_B;
    // xh: fp16 copy of x, live through euler step 1
    u16*   xh    = (u16*)ws;  ws += ROWB_B;
    // evals16 (6.4 MB used) -- dead after finalize -- region reused as z3
    u16*   evals16 = (u16*)ws;
    u16*   z3    = (u16*)ws;  ws += (size_t)E * HEADS * 4;   // 12.8 MB region
    float* nsum  = (float*)ws; ws += (size_t)N * HEADS * 4;
    int*   deg   = (int*)ws;   ws += (size_t)N * 4;
    int*   off   = (int*)ws;   ws += ((size_t)(N + 1) * 4 + 255) & ~255ull;
    int*   bcur  = (int*)ws;   ws += ((size_t)NBUCK * 4 + 255) & ~255ull;
    int*   part  = (int*)ws;   ws += 256;
    u32*   epack = (u32*)ws;   ws += (size_t)E * 4;   // dst-only CSR, then packed
    u32*   tmp   = (u32*)ws;   ws += (size_t)E * 4;   // bucket-grouped edges
    u16*   Wqt   = (u16*)ws;   ws += (size_t)128 * 128 * 2;
    u16*   Wkt   = (u16*)ws;   ws += (size_t)128 * 128 * 2;

    // zero nsum + deg (contiguous)
    hipMemsetAsync(nsum, 0, (size_t)N * HEADS * 4 + (size_t)N * 4, stream);

    // W -> bf16 transposed
    wprep<<<128, 256, 0, stream>>>(Wq, Wk, Wqt, Wkt);

    // Q/K projections via MFMA (bf16 out) + fp16 copy of x
    gemm_qk_mfma<<<(N + 63) / 64, 256, 0, stream>>>(
        x, Wqt, bq, Wkt, bk, qb, kb, xh, N);

    // degree histogram (by src)
    hist_kernel<<<E / 256, 256, 0, stream>>>(ei, deg);

    // CSR offsets: two-level scan (+ bucket cursors)
    const int nb = (N + 1023) / 1024;
    scan1<<<nb, 1024, 0, stream>>>(deg, off, part, N);
    scan2<<<1, 64, 0, stream>>>(part, off + N, nb);
    scan3<<<nb, 1024, 0, stream>>>(off, bcur, part, N);

    // two-phase binned CSR fill
    bin_edges<<<(E + CHUNK - 1) / CHUNK, 256, 0, stream>>>(ei, bcur, tmp);
    place_edges<<<NBUCK, 256, 0, stream>>>(tmp, off, epack, N);

    // CSR-ordered scores -> exp (bf16) -> segment sums
    score_csr<<<(N * 64 + 255) / 256, 256, 0, stream>>>(
        qb, kb, off, epack, evals16, nsum, N);

    // attention mean, packed in place
    finalize_kernel<<<E / 256, 256, 0, stream>>>(evals16, nsum, epack);

    // 4 Euler steps, fp16 state chain: xh -> z1 -> z2 -> z3 -> out(fp32)
    const int sg = (N * 64 + 255) / 256;
    spmv_h<0><<<sg, 256, 0, stream>>>(xh, z1, nullptr, off, epack, N);
    spmv_h<0><<<sg, 256, 0, stream>>>(z1, z2, nullptr, off, epack, N);
    spmv_h<0><<<sg, 256, 0, stream>>>(z2, z3, nullptr, off, epack, N);
    spmv_h<1><<<sg, 256, 0, stream>>>(z3, nullptr, out, off, epack, N);
}